// Round 4
// baseline (532.573 us; speedup 1.0000x reference)
//
#include <hip/hip_runtime.h>
#include <math.h>

static constexpr int N   = 3072;
static constexpr int DIN = 64;
static constexpr int D   = 128;
static constexpr int H   = 4;
static constexpr int E   = 49152;
#define NEGV  (-4294967295.0f)
#define SCALE (0.08838834764831845f)   // 1/sqrt(128)

typedef unsigned short u16;
typedef __attribute__((ext_vector_type(8))) short short8;
typedef __attribute__((ext_vector_type(4))) float f32x4;
typedef __attribute__((ext_vector_type(4))) unsigned short u16x4;

__device__ __forceinline__ u16 f2bf(float f){           // RNE float->bf16
  unsigned int u = __float_as_uint(f);
  u += 0x7fff + ((u >> 16) & 1);
  return (u16)(u >> 16);
}
__device__ __forceinline__ float bf2f(u16 u){
  return __uint_as_float(((unsigned int)u) << 16);
}

// ---------------------------------------------------------------- deg / h0
__global__ void k_zero_deg(int* __restrict__ deg){
  int i = blockIdx.x*blockDim.x + threadIdx.x;
  if(i < N) deg[i] = 0;
}

__global__ void k_deg(const int* __restrict__ ei, int* __restrict__ deg){
  int e = blockIdx.x*blockDim.x + threadIdx.x;
  if(e < E) atomicAdd(&deg[ei[E + e]], 1);
}

__global__ void k_h0(const float* __restrict__ x, const float* __restrict__ nodeW,
                     const float* __restrict__ nodeb, const float* __restrict__ degemb,
                     const int* __restrict__ deg, float* __restrict__ mask,
                     float* __restrict__ h){
  const int i = blockIdx.x, t = threadIdx.x;
  float xv = x[i*DIN + t];
  float s = xv;
  #pragma unroll
  for(int o=32;o;o>>=1) s += __shfl_xor(s, o);
  if(t == 0) mask[i] = (s != 0.0f) ? 1.0f : 0.0f;
  __shared__ float xr[DIN];
  xr[t] = xv;
  __syncthreads();
  int dg = deg[i]; dg = dg > N-1 ? N-1 : dg;
  float a0 = nodeb[t]      + degemb[dg*D + t];
  float a1 = nodeb[t + 64] + degemb[dg*D + t + 64];
  #pragma unroll
  for(int u=0; u<DIN; ++u){
    float xu = xr[u];
    a0 = fmaf(xu, nodeW[u*D + t],      a0);
    a1 = fmaf(xu, nodeW[u*D + t + 64], a1);
  }
  h[i*D + t]      = a0;
  h[i*D + t + 64] = a1;
}

// ---------------------------------------------------------------- bias (masked, bf16)
__global__ void k_bias(const int* __restrict__ spl, const float* __restrict__ ef,
                       const float* __restrict__ spe, const float* __restrict__ eW,
                       const float* __restrict__ eb, const float* __restrict__ mask,
                       u16* __restrict__ biasm){
  int idx = blockIdx.x*blockDim.x + threadIdx.x;   // < N*N
  int i = idx / N, j = idx % N;
  float wm0 = (eW[0] + eW[1] + eW[2] + eW[3])  * 0.25f;
  float wm1 = (eW[4] + eW[5] + eW[6] + eW[7])  * 0.25f;
  float wm2 = (eW[8] + eW[9] + eW[10]+ eW[11]) * 0.25f;
  float wm3 = (eW[12]+ eW[13]+ eW[14]+ eW[15]) * 0.25f;
  float bm  = (eb[0] + eb[1] + eb[2] + eb[3])  * 0.25f;
  float4 e4 = reinterpret_cast<const float4*>(ef)[idx];
  float em = fmaf(e4.x, wm0, fmaf(e4.y, wm1, fmaf(e4.z, wm2, fmaf(e4.w, wm3, bm))));
  float b = spe[spl[idx]] + em;
  float mk = mask[i]*mask[j];
  biasm[idx] = f2bf((mk != 0.0f) ? b : NEGV);
}

// ---------------------------------------------------------------- layernorm
__global__ void k_ln(const float* __restrict__ in, const float* __restrict__ g,
                     const float* __restrict__ b, float* __restrict__ out){
  const int w = threadIdx.x >> 6, lane = threadIdx.x & 63;
  const int row = blockIdx.x*4 + w;
  const float* r = in + row*D;
  float v0 = r[lane], v1 = r[lane + 64];
  float s = v0 + v1, sq = v0*v0 + v1*v1;
  #pragma unroll
  for(int o=32;o;o>>=1){ s += __shfl_xor(s, o); sq += __shfl_xor(sq, o); }
  float mean = s*(1.0f/128.0f);
  float var  = sq*(1.0f/128.0f) - mean*mean;
  float inv  = rsqrtf(var + 1e-5f);
  out[row*D + lane]      = (v0 - mean)*inv*g[lane]      + b[lane];
  out[row*D + lane + 64] = (v1 - mean)*inv*g[lane + 64] + b[lane + 64];
}

// ---------------------------------------------------------------- fp32 SGEMM 64x64 tile
template<bool RES, bool BF16OUT>
__device__ __forceinline__ void gemm_body(const float* __restrict__ A, const float* __restrict__ B,
                                          const float* __restrict__ bias, const float* __restrict__ res,
                                          void* __restrict__ Cv, int M, int Nc, int K){
  __shared__ float As[16][72];
  __shared__ float Bs[16][72];
  const int tid  = threadIdx.x;
  const int m0   = blockIdx.x*64, n0 = blockIdx.y*64;
  const int tx   = tid & 15, ty = tid >> 4;
  const int arow = tid >> 2, akq = tid & 3;
  const int brow = tid >> 4, bnq = tid & 15;
  float acc[4][4] = {};
  for(int k0 = 0; k0 < K; k0 += 16){
    __syncthreads();
    float4 av = *reinterpret_cast<const float4*>(A + (m0 + arow)*K + k0 + akq*4);
    As[akq*4+0][arow] = av.x; As[akq*4+1][arow] = av.y;
    As[akq*4+2][arow] = av.z; As[akq*4+3][arow] = av.w;
    float4 bv = *reinterpret_cast<const float4*>(B + (k0 + brow)*Nc + n0 + bnq*4);
    *reinterpret_cast<float4*>(&Bs[brow][bnq*4]) = bv;
    __syncthreads();
    #pragma unroll
    for(int kk = 0; kk < 16; ++kk){
      float4 a4 = *reinterpret_cast<const float4*>(&As[kk][ty*4]);
      float4 b4 = *reinterpret_cast<const float4*>(&Bs[kk][tx*4]);
      float a_[4] = {a4.x, a4.y, a4.z, a4.w};
      float b_[4] = {b4.x, b4.y, b4.z, b4.w};
      #pragma unroll
      for(int i=0;i<4;i++)
        #pragma unroll
        for(int j=0;j<4;j++)
          acc[i][j] = fmaf(a_[i], b_[j], acc[i][j]);
    }
  }
  #pragma unroll
  for(int i=0;i<4;i++){
    int r = m0 + ty*4 + i;
    int c = n0 + tx*4;
    float4 bi = *reinterpret_cast<const float4*>(bias + c);
    float o0 = acc[i][0] + bi.x, o1 = acc[i][1] + bi.y;
    float o2 = acc[i][2] + bi.z, o3 = acc[i][3] + bi.w;
    if(RES){
      float4 rv = *reinterpret_cast<const float4*>(res + r*Nc + c);
      o0 += rv.x; o1 += rv.y; o2 += rv.z; o3 += rv.w;
    }
    if(BF16OUT){
      u16x4 u; u.x = f2bf(o0); u.y = f2bf(o1); u.z = f2bf(o2); u.w = f2bf(o3);
      *reinterpret_cast<u16x4*>((u16*)Cv + (size_t)r*Nc + c) = u;
    }else{
      *reinterpret_cast<float4*>((float*)Cv + (size_t)r*Nc + c) = make_float4(o0,o1,o2,o3);
    }
  }
}

template<bool RES>
__global__ __launch_bounds__(256) void k_gemm(const float* __restrict__ A, const float* __restrict__ B,
                                              const float* __restrict__ bias, const float* __restrict__ res,
                                              float* __restrict__ C, int M, int Nc, int K){
  gemm_body<RES,false>(A, B, bias, res, C, M, Nc, K);
}

// grid.z = which*4 + head (0=q 1=k 2=v) — bf16 row-major output
__global__ __launch_bounds__(256) void k_qkv(const float* __restrict__ xln,
    const float* __restrict__ Wq, const float* __restrict__ Wk, const float* __restrict__ Wv,
    const float* __restrict__ bq, const float* __restrict__ bk, const float* __restrict__ bv,
    u16* __restrict__ q, u16* __restrict__ k, u16* __restrict__ v, int l){
  const int z = blockIdx.z, which = z >> 2, head = z & 3;
  const float* W; const float* bb; u16* out;
  if(which == 0){ W = Wq; bb = bq; out = q; }
  else if(which == 1){ W = Wk; bb = bk; out = k; }
  else { W = Wv; bb = bv; out = v; }
  W  += (l*H + head)*D*D;
  bb += (l*H + head)*D;
  out += (size_t)head*(N*D);
  gemm_body<false,true>(xln, W, bb, nullptr, out, N, D, D);
}

// ---------------------------------------------------------------- V transpose: [h][n][d] -> [h][d][n]
__global__ __launch_bounds__(256) void k_vt(const u16* __restrict__ vb, u16* __restrict__ vT){
  __shared__ u16 t[32][33];
  const int n0 = blockIdx.x*32, d0 = blockIdx.y*32, head = blockIdx.z;
  const int tid = threadIdx.x;
  #pragma unroll
  for(int i=0;i<4;i++){
    int idx = tid + i*256, r = idx >> 5, c = idx & 31;
    t[r][c] = vb[((size_t)head*N + n0 + r)*D + d0 + c];
  }
  __syncthreads();
  #pragma unroll
  for(int i=0;i<4;i++){
    int idx = tid + i*256, r = idx >> 5, c = idx & 31;
    vT[((size_t)head*D + d0 + r)*N + n0 + c] = t[c][r];
  }
}

// ---------------------------------------------------------------- MFMA flash attention (swapped QK^T)
// 4 waves/block, 1 q-tile (16 rows) per wave; grid (N/64, H, SPLIT).
// S = mfma(A=K, B=Q): lane(g4,l16) holds S[key=j0+g4*4+rg][q=r0+l16] — row softmax is
// in-lane over 8 regs + 2 shuffles (xor16/32). m/lsum are per-lane scalars (q=l16).
// K+bias prefetched one tile ahead; V issued at loop top. Defer-rescale THR=8.
__global__ __launch_bounds__(256) void k_attn(const u16* __restrict__ q, const u16* __restrict__ k,
                     const u16* __restrict__ vT, const u16* __restrict__ biasm,
                     float* __restrict__ opart, float* __restrict__ mpart, float* __restrict__ lpart,
                     int kvlen){
  const int tid  = threadIdx.x;
  const int w    = tid >> 6;
  const int lane = tid & 63;
  const int g4 = lane >> 4, l16 = lane & 15;
  const int qt   = blockIdx.x*4 + w;
  const int head = blockIdx.y, sp = blockIdx.z;
  const int r0 = qt*16;
  __shared__ u16 P[4][16][40];                     // per-wave, padded stride

  const u16* qbase = q + ((size_t)head*N + r0)*D;
  short8 qf[4];
  #pragma unroll
  for(int c=0;c<4;c++)
    qf[c] = *reinterpret_cast<const short8*>(qbase + l16*D + c*32 + g4*8);

  f32x4 o[8];
  #pragma unroll
  for(int dt=0;dt<8;dt++) o[dt] = (f32x4){0.f,0.f,0.f,0.f};
  float m = -INFINITY, lsum = 0.0f;

  const u16* kh   = k  + (size_t)head*N*D;
  const u16* vh   = vT + (size_t)head*D*N + (size_t)l16*N;
  const u16* brow = biasm + (size_t)(r0 + l16)*N;  // this lane's q-row
  const int kv0 = sp*kvlen, kv1 = kv0 + kvlen;

  // prefetch tile 0: K fragments + bias
  short8 kfc[8];
  {
    const u16* kb0 = kh + (size_t)(kv0 + l16)*D + g4*8;
    #pragma unroll
    for(int c=0;c<4;c++){
      kfc[c]   = *reinterpret_cast<const short8*>(kb0 + c*32);
      kfc[4+c] = *reinterpret_cast<const short8*>(kb0 + 16*D + c*32);
    }
  }
  u16x4 bA = *reinterpret_cast<const u16x4*>(brow + kv0 + g4*4);
  u16x4 bB = *reinterpret_cast<const u16x4*>(brow + kv0 + 16 + g4*4);

  for(int j0 = kv0; j0 < kv1; j0 += 32){
    const int jn = (j0 + 32 < kv1) ? j0 + 32 : kv0;   // wrap keeps addrs valid; dead on last iter
    // ---- issue next-tile K + bias (hidden under this tile's compute)
    short8 kfn[8];
    {
      const u16* kbn = kh + (size_t)(jn + l16)*D + g4*8;
      #pragma unroll
      for(int c=0;c<4;c++){
        kfn[c]   = *reinterpret_cast<const short8*>(kbn + c*32);
        kfn[4+c] = *reinterpret_cast<const short8*>(kbn + 16*D + c*32);
      }
    }
    u16x4 bAn = *reinterpret_cast<const u16x4*>(brow + jn + g4*4);
    u16x4 bBn = *reinterpret_cast<const u16x4*>(brow + jn + 16 + g4*4);
    // ---- issue current V (consumed after softmax)
    short8 vf[8];
    {
      const u16* vb = vh + j0 + g4*8;
      #pragma unroll
      for(int dt=0;dt<8;dt++)
        vf[dt] = *reinterpret_cast<const short8*>(vb + (size_t)dt*16*N);
    }
    // ---- QK^T (swapped): S[key][q]
    f32x4 sA = (f32x4){0.f,0.f,0.f,0.f}, sB = sA;
    __builtin_amdgcn_s_setprio(1);
    #pragma unroll
    for(int c=0;c<4;c++){
      sA = __builtin_amdgcn_mfma_f32_16x16x32_bf16(kfc[c],   qf[c], sA, 0, 0, 0);
      sB = __builtin_amdgcn_mfma_f32_16x16x32_bf16(kfc[4+c], qf[c], sB, 0, 0, 0);
    }
    __builtin_amdgcn_s_setprio(0);
    // ---- scale + bias (all 8 scores belong to q = l16; keys g4*4+rg / +16)
    sA[0] = fmaf(sA[0], SCALE, bf2f(bA.x)); sA[1] = fmaf(sA[1], SCALE, bf2f(bA.y));
    sA[2] = fmaf(sA[2], SCALE, bf2f(bA.z)); sA[3] = fmaf(sA[3], SCALE, bf2f(bA.w));
    sB[0] = fmaf(sB[0], SCALE, bf2f(bB.x)); sB[1] = fmaf(sB[1], SCALE, bf2f(bB.y));
    sB[2] = fmaf(sB[2], SCALE, bf2f(bB.z)); sB[3] = fmaf(sB[3], SCALE, bf2f(bB.w));
    // ---- row max: in-lane over 8, then across g4 groups (2 shuffles)
    float pmax = fmaxf(fmaxf(fmaxf(sA[0],sA[1]), fmaxf(sA[2],sA[3])),
                       fmaxf(fmaxf(sB[0],sB[1]), fmaxf(sB[2],sB[3])));
    pmax = fmaxf(pmax, __shfl_xor(pmax, 16));
    pmax = fmaxf(pmax, __shfl_xor(pmax, 32));
    // ---- defer-rescale (THR=8)
    if(!__all(pmax - m <= 8.0f)){
      float mnew = fmaxf(m, pmax);
      float corr = __expf(m - mnew);
      lsum *= corr;
      // O's q lives in regs (g4*4+rg) — broadcast corr from the matching lane
      float c0 = __shfl(corr, (lane & 48) | (g4*4 + 0));
      float c1 = __shfl(corr, (lane & 48) | (g4*4 + 1));
      float c2 = __shfl(corr, (lane & 48) | (g4*4 + 2));
      float c3 = __shfl(corr, (lane & 48) | (g4*4 + 3));
      #pragma unroll
      for(int dt=0;dt<8;dt++){
        o[dt][0] *= c0; o[dt][1] *= c1; o[dt][2] *= c2; o[dt][3] *= c3;
      }
      m = mnew;
    }
    // ---- P = exp(S - m) (bounded by e^8), in-lane sum + 2 shuffles
    f32x4 pA, pB;
    #pragma unroll
    for(int rg=0;rg<4;rg++){ pA[rg] = __expf(sA[rg] - m); pB[rg] = __expf(sB[rg] - m); }
    float ps = (pA[0]+pA[1]) + (pA[2]+pA[3]) + ((pB[0]+pB[1]) + (pB[2]+pB[3]));
    ps += __shfl_xor(ps, 16);
    ps += __shfl_xor(ps, 32);
    lsum += ps;
    // ---- pack P -> LDS (2 x b64 write, 1 x b128 read)
    u16x4 wa, wb;
    wa.x = f2bf(pA[0]); wa.y = f2bf(pA[1]); wa.z = f2bf(pA[2]); wa.w = f2bf(pA[3]);
    wb.x = f2bf(pB[0]); wb.y = f2bf(pB[1]); wb.z = f2bf(pB[2]); wb.w = f2bf(pB[3]);
    *reinterpret_cast<u16x4*>(&P[w][l16][g4*4])      = wa;
    *reinterpret_cast<u16x4*>(&P[w][l16][16 + g4*4]) = wb;
    short8 pf = *reinterpret_cast<const short8*>(&P[w][l16][g4*8]);
    // ---- PV: A = P[q][k], B = vT[d][k]
    __builtin_amdgcn_s_setprio(1);
    #pragma unroll
    for(int dt=0;dt<8;dt++)
      o[dt] = __builtin_amdgcn_mfma_f32_16x16x32_bf16(pf, vf[dt], o[dt], 0, 0, 0);
    __builtin_amdgcn_s_setprio(0);
    // ---- rotate prefetched regs
    #pragma unroll
    for(int c=0;c<8;c++) kfc[c] = kfn[c];
    bA = bAn; bB = bBn;
  }

  // ---- store partials (unnormalized O, m, l)
  float* ob = opart + ((size_t)((sp*H + head)*N) + r0)*D;
  #pragma unroll
  for(int dt=0;dt<8;dt++){
    #pragma unroll
    for(int rg=0;rg<4;rg++)
      ob[(size_t)(g4*4+rg)*D + dt*16 + l16] = o[dt][rg];
  }
  if(g4 == 0){
    mpart[(size_t)(sp*H + head)*N + r0 + l16] = m;
    lpart[(size_t)(sp*H + head)*N + r0 + l16] = lsum;
  }
}

// ---------------------------------------------------------------- split-K combine
template<int S>
__global__ __launch_bounds__(256) void k_comb(const float* __restrict__ opart,
                      const float* __restrict__ mpart, const float* __restrict__ lpart,
                      const float* __restrict__ mask, float* __restrict__ ocat){
  int idx = blockIdx.x*256 + threadIdx.x;          // < H*N*D
  int d = idx & (D-1);
  int r = (idx >> 7) % N;
  int h = idx / (N*D);
  float mv[S], lv[S];
  float M = -INFINITY;
  #pragma unroll
  for(int s=0;s<S;s++){
    size_t p = (size_t)(s*H + h)*N + r;
    mv[s] = mpart[p]; lv[s] = lpart[p];
    M = fmaxf(M, mv[s]);
  }
  float denom = 0.f, val = 0.f;
  #pragma unroll
  for(int s=0;s<S;s++){
    size_t p = (size_t)(s*H + h)*N + r;
    float wgt = __expf(mv[s] - M);
    denom = fmaf(lv[s], wgt, denom);
    val   = fmaf(opart[p*D + d], wgt, val);
  }
  ocat[(size_t)r*(H*D) + h*D + d] = val * (mask[r] / denom);
}

// ---------------------------------------------------------------- launch
extern "C" void kernel_launch(void* const* d_in, const int* in_sizes, int n_in,
                              void* d_out, int out_size, void* d_ws, size_t ws_size,
                              hipStream_t stream){
  const float* x      = (const float*)d_in[0];
  const int*   ei     = (const int*)  d_in[1];
  const int*   spl    = (const int*)  d_in[2];
  const float* ef     = (const float*)d_in[3];
  const float* nodeW  = (const float*)d_in[4];
  const float* nodeb  = (const float*)d_in[5];
  const float* degemb = (const float*)d_in[6];
  const float* spe    = (const float*)d_in[7];
  const float* eW     = (const float*)d_in[8];
  const float* eb     = (const float*)d_in[9];
  const float* ln1g   = (const float*)d_in[10];
  const float* ln1b   = (const float*)d_in[11];
  const float* Wq     = (const float*)d_in[12];
  const float* bq     = (const float*)d_in[13];
  const float* Wk     = (const float*)d_in[14];
  const float* bk     = (const float*)d_in[15];
  const float* Wv     = (const float*)d_in[16];
  const float* bv     = (const float*)d_in[17];
  const float* Wo     = (const float*)d_in[18];
  const float* bo     = (const float*)d_in[19];
  const float* ln2g   = (const float*)d_in[20];
  const float* ln2b   = (const float*)d_in[21];
  const float* ffW    = (const float*)d_in[22];
  const float* ffb    = (const float*)d_in[23];
  const float* outW   = (const float*)d_in[24];
  const float* outb   = (const float*)d_in[25];

  // pick SPLIT by available workspace (deterministic in ws_size)
  auto needed = [](int s)->size_t{
    size_t fl = 8192 + 3*(size_t)N*D + (size_t)N*H*D;          // fp32 elems
    size_t bf = 4*(size_t)H*N*D + (size_t)N*N;                 // bf16 elems
    size_t pf = (size_t)s*H*N*D + 2*(size_t)s*H*N;             // fp32 partials
    return fl*4 + bf*2 + pf*4;
  };
  int S = 2;
  if(needed(8) <= ws_size) S = 8;
  else if(needed(4) <= ws_size) S = 4;

  float* ws   = (float*)d_ws;
  int*   deg  = (int*)ws;                       // N ints (4096-float slot)
  float* mask = ws + 4096;                      // N (4096-float slot)
  float* h    = ws + 8192;                      // N*D
  float* xln  = h    + N*D;
  float* xout = xln  + N*D;
  float* ocat = xout + N*D;                     // N*H*D fp32
  u16*   qb   = (u16*)(ocat + N*H*D);           // H*N*D bf16 each
  u16*   kb   = qb + (size_t)H*N*D;
  u16*   vb   = kb + (size_t)H*N*D;
  u16*   vT   = vb + (size_t)H*N*D;
  u16*   biasm= vT + (size_t)H*N*D;             // N*N bf16
  float* opart= (float*)(biasm + (size_t)N*N);  // S*H*N*D
  float* mpart= opart + (size_t)S*H*N*D;        // S*H*N
  float* lpart= mpart + (size_t)S*H*N;          // S*H*N

  k_zero_deg<<<(N+255)/256, 256, 0, stream>>>(deg);
  k_deg<<<(E+255)/256, 256, 0, stream>>>(ei, deg);
  k_h0<<<N, 64, 0, stream>>>(x, nodeW, nodeb, degemb, deg, mask, h);
  k_bias<<<(N*N)/256, 256, 0, stream>>>(spl, ef, spe, eW, eb, mask, biasm);

  for(int l = 0; l < 2; ++l){
    k_ln<<<N/4, 256, 0, stream>>>(h, ln1g + l*D, ln1b + l*D, xln);
    k_qkv<<<dim3(N/64, D/64, 12), 256, 0, stream>>>(xln, Wq, Wk, Wv, bq, bk, bv, qb, kb, vb, l);
    k_vt<<<dim3(N/32, D/32, H), 256, 0, stream>>>(vb, vT);
    k_attn<<<dim3(N/64, H, S), 256, 0, stream>>>(qb, kb, vT, biasm, opart, mpart, lpart, N/S);
    if(S == 8)      k_comb<8><<<(H*N*D)/256, 256, 0, stream>>>(opart, mpart, lpart, mask, ocat);
    else if(S == 4) k_comb<4><<<(H*N*D)/256, 256, 0, stream>>>(opart, mpart, lpart, mask, ocat);
    else            k_comb<2><<<(H*N*D)/256, 256, 0, stream>>>(opart, mpart, lpart, mask, ocat);
    k_gemm<true><<<dim3(N/64, D/64), 256, 0, stream>>>(ocat, Wo + l*(H*D*D), bo + l*D, h, xout, N, D, H*D);
    k_ln<<<N/4, 256, 0, stream>>>(xout, ln2g + l*D, ln2b + l*D, xln);
    k_gemm<true><<<dim3(N/64, D/64), 256, 0, stream>>>(xln, ffW + l*D*D, ffb + l*D, xout, h, N, D, D);
  }
  k_gemm<false><<<dim3(N/64, D/64), 256, 0, stream>>>(h, outW, outb, nullptr, (float*)d_out, N, D, D);
}

// Round 5
// 291.120 us; speedup vs baseline: 1.8294x; 1.8294x over previous
//
#include <hip/hip_runtime.h>
#include <math.h>

static constexpr int N   = 3072;
static constexpr int DIN = 64;
static constexpr int D   = 128;
static constexpr int H   = 4;
static constexpr int E   = 49152;
#define NEGV  (-4294967295.0f)
#define SCALE (0.08838834764831845f)   // 1/sqrt(128)

typedef unsigned short u16;
typedef __attribute__((ext_vector_type(8))) short short8;
typedef __attribute__((ext_vector_type(4))) float f32x4;
typedef __attribute__((ext_vector_type(4))) unsigned short u16x4;

__device__ __forceinline__ u16 f2bf(float f){           // RNE float->bf16
  unsigned int u = __float_as_uint(f);
  u += 0x7fff + ((u >> 16) & 1);
  return (u16)(u >> 16);
}
__device__ __forceinline__ float bf2f(u16 u){
  return __uint_as_float(((unsigned int)u) << 16);
}

// ---------------------------------------------------------------- deg / h0
__global__ void k_zero_deg(int* __restrict__ deg){
  int i = blockIdx.x*blockDim.x + threadIdx.x;
  if(i < N) deg[i] = 0;
}

__global__ void k_deg(const int* __restrict__ ei, int* __restrict__ deg){
  int e = blockIdx.x*blockDim.x + threadIdx.x;
  if(e < E) atomicAdd(&deg[ei[E + e]], 1);
}

__global__ void k_h0(const float* __restrict__ x, const float* __restrict__ nodeW,
                     const float* __restrict__ nodeb, const float* __restrict__ degemb,
                     const int* __restrict__ deg, float* __restrict__ mask,
                     float* __restrict__ h){
  const int i = blockIdx.x, t = threadIdx.x;
  float xv = x[i*DIN + t];
  float s = xv;
  #pragma unroll
  for(int o=32;o;o>>=1) s += __shfl_xor(s, o);
  if(t == 0) mask[i] = (s != 0.0f) ? 1.0f : 0.0f;
  __shared__ float xr[DIN];
  xr[t] = xv;
  __syncthreads();
  int dg = deg[i]; dg = dg > N-1 ? N-1 : dg;
  float a0 = nodeb[t]      + degemb[dg*D + t];
  float a1 = nodeb[t + 64] + degemb[dg*D + t + 64];
  #pragma unroll
  for(int u=0; u<DIN; ++u){
    float xu = xr[u];
    a0 = fmaf(xu, nodeW[u*D + t],      a0);
    a1 = fmaf(xu, nodeW[u*D + t + 64], a1);
  }
  h[i*D + t]      = a0;
  h[i*D + t + 64] = a1;
}

// ---------------------------------------------------------------- bias (masked, bf16)
__global__ void k_bias(const int* __restrict__ spl, const float* __restrict__ ef,
                       const float* __restrict__ spe, const float* __restrict__ eW,
                       const float* __restrict__ eb, const float* __restrict__ mask,
                       u16* __restrict__ biasm){
  int idx = blockIdx.x*blockDim.x + threadIdx.x;   // < N*N
  int i = idx / N, j = idx % N;
  float wm0 = (eW[0] + eW[1] + eW[2] + eW[3])  * 0.25f;
  float wm1 = (eW[4] + eW[5] + eW[6] + eW[7])  * 0.25f;
  float wm2 = (eW[8] + eW[9] + eW[10]+ eW[11]) * 0.25f;
  float wm3 = (eW[12]+ eW[13]+ eW[14]+ eW[15]) * 0.25f;
  float bm  = (eb[0] + eb[1] + eb[2] + eb[3])  * 0.25f;
  float4 e4 = reinterpret_cast<const float4*>(ef)[idx];
  float em = fmaf(e4.x, wm0, fmaf(e4.y, wm1, fmaf(e4.z, wm2, fmaf(e4.w, wm3, bm))));
  float b = spe[spl[idx]] + em;
  float mk = mask[i]*mask[j];
  biasm[idx] = f2bf((mk != 0.0f) ? b : NEGV);
}

// ---------------------------------------------------------------- layernorm
__global__ void k_ln(const float* __restrict__ in, const float* __restrict__ g,
                     const float* __restrict__ b, float* __restrict__ out){
  const int w = threadIdx.x >> 6, lane = threadIdx.x & 63;
  const int row = blockIdx.x*4 + w;
  const float* r = in + row*D;
  float v0 = r[lane], v1 = r[lane + 64];
  float s = v0 + v1, sq = v0*v0 + v1*v1;
  #pragma unroll
  for(int o=32;o;o>>=1){ s += __shfl_xor(s, o); sq += __shfl_xor(sq, o); }
  float mean = s*(1.0f/128.0f);
  float var  = sq*(1.0f/128.0f) - mean*mean;
  float inv  = rsqrtf(var + 1e-5f);
  out[row*D + lane]      = (v0 - mean)*inv*g[lane]      + b[lane];
  out[row*D + lane + 64] = (v1 - mean)*inv*g[lane + 64] + b[lane + 64];
}

// ---------------------------------------------------------------- fp32 SGEMM 64x64 tile
template<bool RES, bool BF16OUT>
__device__ __forceinline__ void gemm_body(const float* __restrict__ A, const float* __restrict__ B,
                                          const float* __restrict__ bias, const float* __restrict__ res,
                                          void* __restrict__ Cv, int M, int Nc, int K){
  __shared__ float As[16][72];
  __shared__ float Bs[16][72];
  const int tid  = threadIdx.x;
  const int m0   = blockIdx.x*64, n0 = blockIdx.y*64;
  const int tx   = tid & 15, ty = tid >> 4;
  const int arow = tid >> 2, akq = tid & 3;
  const int brow = tid >> 4, bnq = tid & 15;
  float acc[4][4] = {};
  for(int k0 = 0; k0 < K; k0 += 16){
    __syncthreads();
    float4 av = *reinterpret_cast<const float4*>(A + (m0 + arow)*K + k0 + akq*4);
    As[akq*4+0][arow] = av.x; As[akq*4+1][arow] = av.y;
    As[akq*4+2][arow] = av.z; As[akq*4+3][arow] = av.w;
    float4 bv = *reinterpret_cast<const float4*>(B + (k0 + brow)*Nc + n0 + bnq*4);
    *reinterpret_cast<float4*>(&Bs[brow][bnq*4]) = bv;
    __syncthreads();
    #pragma unroll
    for(int kk = 0; kk < 16; ++kk){
      float4 a4 = *reinterpret_cast<const float4*>(&As[kk][ty*4]);
      float4 b4 = *reinterpret_cast<const float4*>(&Bs[kk][tx*4]);
      float a_[4] = {a4.x, a4.y, a4.z, a4.w};
      float b_[4] = {b4.x, b4.y, b4.z, b4.w};
      #pragma unroll
      for(int i=0;i<4;i++)
        #pragma unroll
        for(int j=0;j<4;j++)
          acc[i][j] = fmaf(a_[i], b_[j], acc[i][j]);
    }
  }
  #pragma unroll
  for(int i=0;i<4;i++){
    int r = m0 + ty*4 + i;
    int c = n0 + tx*4;
    float4 bi = *reinterpret_cast<const float4*>(bias + c);
    float o0 = acc[i][0] + bi.x, o1 = acc[i][1] + bi.y;
    float o2 = acc[i][2] + bi.z, o3 = acc[i][3] + bi.w;
    if(RES){
      float4 rv = *reinterpret_cast<const float4*>(res + r*Nc + c);
      o0 += rv.x; o1 += rv.y; o2 += rv.z; o3 += rv.w;
    }
    if(BF16OUT){
      u16x4 u; u.x = f2bf(o0); u.y = f2bf(o1); u.z = f2bf(o2); u.w = f2bf(o3);
      *reinterpret_cast<u16x4*>((u16*)Cv + (size_t)r*Nc + c) = u;
    }else{
      *reinterpret_cast<float4*>((float*)Cv + (size_t)r*Nc + c) = make_float4(o0,o1,o2,o3);
    }
  }
}

template<bool RES>
__global__ __launch_bounds__(256) void k_gemm(const float* __restrict__ A, const float* __restrict__ B,
                                              const float* __restrict__ bias, const float* __restrict__ res,
                                              float* __restrict__ C, int M, int Nc, int K){
  gemm_body<RES,false>(A, B, bias, res, C, M, Nc, K);
}

// grid.z = which*4 + head (0=q 1=k 2=v) — bf16 row-major output
__global__ __launch_bounds__(256) void k_qkv(const float* __restrict__ xln,
    const float* __restrict__ Wq, const float* __restrict__ Wk, const float* __restrict__ Wv,
    const float* __restrict__ bq, const float* __restrict__ bk, const float* __restrict__ bv,
    u16* __restrict__ q, u16* __restrict__ k, u16* __restrict__ v, int l){
  const int z = blockIdx.z, which = z >> 2, head = z & 3;
  const float* W; const float* bb; u16* out;
  if(which == 0){ W = Wq; bb = bq; out = q; }
  else if(which == 1){ W = Wk; bb = bk; out = k; }
  else { W = Wv; bb = bv; out = v; }
  W  += (l*H + head)*D*D;
  bb += (l*H + head)*D;
  out += (size_t)head*(N*D);
  gemm_body<false,true>(xln, W, bb, nullptr, out, N, D, D);
}

// ---------------------------------------------------------------- V transpose: [h][n][d] -> [h][d][n]
__global__ __launch_bounds__(256) void k_vt(const u16* __restrict__ vb, u16* __restrict__ vT){
  __shared__ u16 t[32][33];
  const int n0 = blockIdx.x*32, d0 = blockIdx.y*32, head = blockIdx.z;
  const int tid = threadIdx.x;
  #pragma unroll
  for(int i=0;i<4;i++){
    int idx = tid + i*256, r = idx >> 5, c = idx & 31;
    t[r][c] = vb[((size_t)head*N + n0 + r)*D + d0 + c];
  }
  __syncthreads();
  #pragma unroll
  for(int i=0;i<4;i++){
    int idx = tid + i*256, r = idx >> 5, c = idx & 31;
    vT[((size_t)head*D + d0 + r)*N + n0 + c] = t[c][r];
  }
}

// ---------------------------------------------------------------- MFMA flash attention, LDS-staged K/V
// Block = 256 thr (4 waves), 64 q-rows (16/wave); grid (N/64, H, SPLIT).
// Per 64-key step: cooperatively reg-stage K-tile (64x128 bf16) and vT-tile
// (128d x 64key, packed 2 segs/row) into LDS; both laid out [64 rows][16x16B chunks]
// with 4-bit row XOR swizzle (chunk ^= row&15) -> <=4-way ds_read_b128 conflicts.
// Inner 32-key math identical to verified R4: S=mfma(K,Q) -> S[key=g4*4+rg][q=l16];
// in-lane softmax + 2 shuffles; defer-rescale THR=8; P via padded LDS; PV=mfma(P,vT).
__global__ __launch_bounds__(256) void k_attn(const u16* __restrict__ q, const u16* __restrict__ k,
                     const u16* __restrict__ vT, const u16* __restrict__ biasm,
                     float* __restrict__ opart, float* __restrict__ mpart, float* __restrict__ lpart,
                     int kvlen){
  const int tid  = threadIdx.x;
  const int w    = tid >> 6;
  const int lane = tid & 63;
  const int g4 = lane >> 4, l16 = lane & 15;
  const int head = blockIdx.y, sp = blockIdx.z;
  const int r0 = blockIdx.x*64 + w*16;
  __shared__ u16 Ks[64*128];          // [key][128 dims], swizzled
  __shared__ u16 Vs[64*128];          // [d&63][seg=d>>6 | 64 keys], swizzled
  __shared__ u16 P[4][16][40];        // per-wave P, padded stride

  // Q fragments (once): row-major 16B loads
  const u16* qbase = q + ((size_t)head*N + r0)*D;
  short8 qf[4];
  #pragma unroll
  for(int c=0;c<4;c++)
    qf[c] = *reinterpret_cast<const short8*>(qbase + l16*D + c*32 + g4*8);

  f32x4 o[8];
  #pragma unroll
  for(int dt=0;dt<8;dt++) o[dt] = (f32x4){0.f,0.f,0.f,0.f};
  float m = -INFINITY, lsum = 0.0f;

  const u16* kh   = k  + (size_t)head*N*D;
  const u16* vTh  = vT + (size_t)head*D*N;
  const u16* brow = biasm + (size_t)(r0 + l16)*N;  // this lane's q-row
  const int kv0 = sp*kvlen;

  // staging decomposition (coalesced 16B per thread)
  const int krow = tid >> 4, kch = tid & 15;       // K: +it*16 rows
  const int vrow = tid >> 3, vch = tid & 7;        // vT: +it*32 d-rows

  for(int j0 = kv0; j0 < kv0 + kvlen; j0 += 64){
    // ---- global loads into regs (coalesced)
    short8 kreg[4], vreg[4];
    #pragma unroll
    for(int it=0; it<4; ++it)
      kreg[it] = *reinterpret_cast<const short8*>(kh + (size_t)(j0 + it*16 + krow)*D + kch*8);
    #pragma unroll
    for(int it=0; it<4; ++it)
      vreg[it] = *reinterpret_cast<const short8*>(vTh + (size_t)(it*32 + vrow)*N + j0 + vch*8);
    // bias for this step's 64 keys (4-key granule per reg-group)
    u16x4 bb[4];
    #pragma unroll
    for(int z=0; z<4; ++z)
      bb[z] = *reinterpret_cast<const u16x4*>(brow + j0 + z*16 + g4*4);

    __syncthreads();                  // prev step's LDS reads done
    #pragma unroll
    for(int it=0; it<4; ++it){
      int row = it*16 + krow;
      *reinterpret_cast<short8*>(&Ks[row*128 + ((kch ^ (row&15))*8)]) = kreg[it];
    }
    #pragma unroll
    for(int it=0; it<4; ++it){
      int d = it*32 + vrow;
      int row = d & 63, ch = ((d>>6)<<3) | vch;
      *reinterpret_cast<short8*>(&Vs[row*128 + ((ch ^ (row&15))*8)]) = vreg[it];
    }
    __syncthreads();                  // tiles ready

    // ---- two 32-key halves
    #pragma unroll
    for(int ks=0; ks<2; ++ks){
      // K fragments from LDS (rows ks*32+l16, ks*32+16+l16)
      short8 kf[8];
      const int rowA = ks*32 + l16, rowB = rowA + 16;   // rowA&15 == rowB&15 == l16
      #pragma unroll
      for(int c=0;c<4;c++){
        kf[c]   = *reinterpret_cast<const short8*>(&Ks[rowA*128 + (((c*4+g4) ^ l16)*8)]);
        kf[4+c] = *reinterpret_cast<const short8*>(&Ks[rowB*128 + (((c*4+g4) ^ l16)*8)]);
      }
      f32x4 sA = (f32x4){0.f,0.f,0.f,0.f}, sB = sA;
      __builtin_amdgcn_s_setprio(1);
      #pragma unroll
      for(int c=0;c<4;c++){
        sA = __builtin_amdgcn_mfma_f32_16x16x32_bf16(kf[c],   qf[c], sA, 0, 0, 0);
        sB = __builtin_amdgcn_mfma_f32_16x16x32_bf16(kf[4+c], qf[c], sB, 0, 0, 0);
      }
      __builtin_amdgcn_s_setprio(0);
      // ---- scale + bias (q = l16; keys ks*32 + g4*4+rg / +16)
      u16x4 bA = bb[2*ks], bB = bb[2*ks+1];
      sA[0] = fmaf(sA[0], SCALE, bf2f(bA.x)); sA[1] = fmaf(sA[1], SCALE, bf2f(bA.y));
      sA[2] = fmaf(sA[2], SCALE, bf2f(bA.z)); sA[3] = fmaf(sA[3], SCALE, bf2f(bA.w));
      sB[0] = fmaf(sB[0], SCALE, bf2f(bB.x)); sB[1] = fmaf(sB[1], SCALE, bf2f(bB.y));
      sB[2] = fmaf(sB[2], SCALE, bf2f(bB.z)); sB[3] = fmaf(sB[3], SCALE, bf2f(bB.w));
      // ---- row max: in-lane over 8, then 2 shuffles across g4 groups
      float pmax = fmaxf(fmaxf(fmaxf(sA[0],sA[1]), fmaxf(sA[2],sA[3])),
                         fmaxf(fmaxf(sB[0],sB[1]), fmaxf(sB[2],sB[3])));
      pmax = fmaxf(pmax, __shfl_xor(pmax, 16));
      pmax = fmaxf(pmax, __shfl_xor(pmax, 32));
      // ---- defer-rescale (THR=8)
      if(!__all(pmax - m <= 8.0f)){
        float mnew = fmaxf(m, pmax);
        float corr = __expf(m - mnew);
        lsum *= corr;
        float c0 = __shfl(corr, (lane & 48) | (g4*4 + 0));
        float c1 = __shfl(corr, (lane & 48) | (g4*4 + 1));
        float c2 = __shfl(corr, (lane & 48) | (g4*4 + 2));
        float c3 = __shfl(corr, (lane & 48) | (g4*4 + 3));
        #pragma unroll
        for(int dt=0;dt<8;dt++){
          o[dt][0] *= c0; o[dt][1] *= c1; o[dt][2] *= c2; o[dt][3] *= c3;
        }
        m = mnew;
      }
      // ---- P = exp(S - m) (bounded by e^8)
      f32x4 pA, pB;
      #pragma unroll
      for(int rg=0;rg<4;rg++){ pA[rg] = __expf(sA[rg] - m); pB[rg] = __expf(sB[rg] - m); }
      float ps = (pA[0]+pA[1]) + (pA[2]+pA[3]) + ((pB[0]+pB[1]) + (pB[2]+pB[3]));
      ps += __shfl_xor(ps, 16);
      ps += __shfl_xor(ps, 32);
      lsum += ps;
      // ---- pack P -> LDS (same-wave write->read, in-order DS pipe)
      u16x4 wa, wb;
      wa.x = f2bf(pA[0]); wa.y = f2bf(pA[1]); wa.z = f2bf(pA[2]); wa.w = f2bf(pA[3]);
      wb.x = f2bf(pB[0]); wb.y = f2bf(pB[1]); wb.z = f2bf(pB[2]); wb.w = f2bf(pB[3]);
      *reinterpret_cast<u16x4*>(&P[w][l16][g4*4])      = wa;
      *reinterpret_cast<u16x4*>(&P[w][l16][16 + g4*4]) = wb;
      short8 pf = *reinterpret_cast<const short8*>(&P[w][l16][g4*8]);
      // ---- PV: B = vT fragments from LDS
      __builtin_amdgcn_s_setprio(1);
      #pragma unroll
      for(int dt=0;dt<8;dt++){
        int d = dt*16 + l16;
        int row = d & 63;                              // row&15 == l16
        int ch  = ((dt>>2)<<3) | (ks<<2) | g4;
        short8 vf = *reinterpret_cast<const short8*>(&Vs[row*128 + ((ch ^ l16)*8)]);
        o[dt] = __builtin_amdgcn_mfma_f32_16x16x32_bf16(pf, vf, o[dt], 0, 0, 0);
      }
      __builtin_amdgcn_s_setprio(0);
    }
  }

  // ---- store partials (unnormalized O, m, l)
  float* ob = opart + ((size_t)((sp*H + head)*N) + r0)*D;
  #pragma unroll
  for(int dt=0;dt<8;dt++){
    #pragma unroll
    for(int rg=0;rg<4;rg++)
      ob[(size_t)(g4*4+rg)*D + dt*16 + l16] = o[dt][rg];
  }
  if(g4 == 0){
    mpart[(size_t)(sp*H + head)*N + r0 + l16] = m;
    lpart[(size_t)(sp*H + head)*N + r0 + l16] = lsum;
  }
}

// ---------------------------------------------------------------- split-K combine
template<int S>
__global__ __launch_bounds__(256) void k_comb(const float* __restrict__ opart,
                      const float* __restrict__ mpart, const float* __restrict__ lpart,
                      const float* __restrict__ mask, float* __restrict__ ocat){
  int idx = blockIdx.x*256 + threadIdx.x;          // < H*N*D
  int d = idx & (D-1);
  int r = (idx >> 7) % N;
  int h = idx / (N*D);
  float mv[S], lv[S];
  float M = -INFINITY;
  #pragma unroll
  for(int s=0;s<S;s++){
    size_t p = (size_t)(s*H + h)*N + r;
    mv[s] = mpart[p]; lv[s] = lpart[p];
    M = fmaxf(M, mv[s]);
  }
  float denom = 0.f, val = 0.f;
  #pragma unroll
  for(int s=0;s<S;s++){
    size_t p = (size_t)(s*H + h)*N + r;
    float wgt = __expf(mv[s] - M);
    denom = fmaf(lv[s], wgt, denom);
    val   = fmaf(opart[p*D + d], wgt, val);
  }
  ocat[(size_t)r*(H*D) + h*D + d] = val * (mask[r] / denom);
}

// ---------------------------------------------------------------- launch
extern "C" void kernel_launch(void* const* d_in, const int* in_sizes, int n_in,
                              void* d_out, int out_size, void* d_ws, size_t ws_size,
                              hipStream_t stream){
  const float* x      = (const float*)d_in[0];
  const int*   ei     = (const int*)  d_in[1];
  const int*   spl    = (const int*)  d_in[2];
  const float* ef     = (const float*)d_in[3];
  const float* nodeW  = (const float*)d_in[4];
  const float* nodeb  = (const float*)d_in[5];
  const float* degemb = (const float*)d_in[6];
  const float* spe    = (const float*)d_in[7];
  const float* eW     = (const float*)d_in[8];
  const float* eb     = (const float*)d_in[9];
  const float* ln1g   = (const float*)d_in[10];
  const float* ln1b   = (const float*)d_in[11];
  const float* Wq     = (const float*)d_in[12];
  const float* bq     = (const float*)d_in[13];
  const float* Wk     = (const float*)d_in[14];
  const float* bk     = (const float*)d_in[15];
  const float* Wv     = (const float*)d_in[16];
  const float* bv     = (const float*)d_in[17];
  const float* Wo     = (const float*)d_in[18];
  const float* bo     = (const float*)d_in[19];
  const float* ln2g   = (const float*)d_in[20];
  const float* ln2b   = (const float*)d_in[21];
  const float* ffW    = (const float*)d_in[22];
  const float* ffb    = (const float*)d_in[23];
  const float* outW   = (const float*)d_in[24];
  const float* outb   = (const float*)d_in[25];

  // SPLIT=4 keeps all 768 attn blocks co-resident (LDS 37KB -> 4 blocks/CU cap)
  auto needed = [](int s)->size_t{
    size_t fl = 8192 + 3*(size_t)N*D + (size_t)N*H*D;          // fp32 elems
    size_t bf = 4*(size_t)H*N*D + (size_t)N*N;                 // bf16 elems
    size_t pf = (size_t)s*H*N*D + 2*(size_t)s*H*N;             // fp32 partials
    return fl*4 + bf*2 + pf*4;
  };
  int S = 2;
  if(needed(4) <= ws_size) S = 4;

  float* ws   = (float*)d_ws;
  int*   deg  = (int*)ws;                       // N ints (4096-float slot)
  float* mask = ws + 4096;                      // N (4096-float slot)
  float* h    = ws + 8192;                      // N*D
  float* xln  = h    + N*D;
  float* xout = xln  + N*D;
  float* ocat = xout + N*D;                     // N*H*D fp32
  u16*   qb   = (u16*)(ocat + N*H*D);           // H*N*D bf16 each
  u16*   kb   = qb + (size_t)H*N*D;
  u16*   vb   = kb + (size_t)H*N*D;
  u16*   vT   = vb + (size_t)H*N*D;
  u16*   biasm= vT + (size_t)H*N*D;             // N*N bf16
  float* opart= (float*)(biasm + (size_t)N*N);  // S*H*N*D
  float* mpart= opart + (size_t)S*H*N*D;        // S*H*N
  float* lpart= mpart + (size_t)S*H*N;          // S*H*N

  k_zero_deg<<<(N+255)/256, 256, 0, stream>>>(deg);
  k_deg<<<(E+255)/256, 256, 0, stream>>>(ei, deg);
  k_h0<<<N, 64, 0, stream>>>(x, nodeW, nodeb, degemb, deg, mask, h);
  k_bias<<<(N*N)/256, 256, 0, stream>>>(spl, ef, spe, eW, eb, mask, biasm);

  for(int l = 0; l < 2; ++l){
    k_ln<<<N/4, 256, 0, stream>>>(h, ln1g + l*D, ln1b + l*D, xln);
    k_qkv<<<dim3(N/64, D/64, 12), 256, 0, stream>>>(xln, Wq, Wk, Wv, bq, bk, bv, qb, kb, vb, l);
    k_vt<<<dim3(N/32, D/32, H), 256, 0, stream>>>(vb, vT);
    k_attn<<<dim3(N/64, H, S), 256, 0, stream>>>(qb, kb, vT, biasm, opart, mpart, lpart, N/S);
    if(S == 4) k_comb<4><<<(H*N*D)/256, 256, 0, stream>>>(opart, mpart, lpart, mask, ocat);
    else       k_comb<2><<<(H*N*D)/256, 256, 0, stream>>>(opart, mpart, lpart, mask, ocat);
    k_gemm<true><<<dim3(N/64, D/64), 256, 0, stream>>>(ocat, Wo + l*(H*D*D), bo + l*D, h, xout, N, D, H*D);
    k_ln<<<N/4, 256, 0, stream>>>(xout, ln2g + l*D, ln2b + l*D, xln);
    k_gemm<true><<<dim3(N/64, D/64), 256, 0, stream>>>(xln, ffW + l*D*D, ffb + l*D, xout, h, N, D, D);
  }
  k_gemm<false><<<dim3(N/64, D/64), 256, 0, stream>>>(h, outW, outb, nullptr, (float*)d_out, N, D, D);
}

// Round 6
// 236.465 us; speedup vs baseline: 2.2522x; 1.2311x over previous
//
#include <hip/hip_runtime.h>
#include <math.h>

static constexpr int N   = 3072;
static constexpr int DIN = 64;
static constexpr int D   = 128;
static constexpr int H   = 4;
static constexpr int E   = 49152;
#define NEGV  (-4294967295.0f)
#define SCALE (0.08838834764831845f)   // 1/sqrt(128)

typedef unsigned short u16;
typedef __attribute__((ext_vector_type(8))) short short8;
typedef __attribute__((ext_vector_type(4))) float f32x4;
typedef __attribute__((ext_vector_type(4))) unsigned short u16x4;

__device__ __forceinline__ u16 f2bf(float f){           // RNE float->bf16
  unsigned int u = __float_as_uint(f);
  u += 0x7fff + ((u >> 16) & 1);
  return (u16)(u >> 16);
}
__device__ __forceinline__ float bf2f(u16 u){
  return __uint_as_float(((unsigned int)u) << 16);
}

// ---------------------------------------------------------------- deg / h0
__global__ void k_zero_deg(int* __restrict__ deg){
  int i = blockIdx.x*blockDim.x + threadIdx.x;
  if(i < N) deg[i] = 0;
}

__global__ void k_deg(const int* __restrict__ ei, int* __restrict__ deg){
  int e = blockIdx.x*blockDim.x + threadIdx.x;
  if(e < E) atomicAdd(&deg[ei[E + e]], 1);
}

__global__ void k_h0(const float* __restrict__ x, const float* __restrict__ nodeW,
                     const float* __restrict__ nodeb, const float* __restrict__ degemb,
                     const int* __restrict__ deg, float* __restrict__ mask,
                     float* __restrict__ h){
  const int i = blockIdx.x, t = threadIdx.x;
  float xv = x[i*DIN + t];
  float s = xv;
  #pragma unroll
  for(int o=32;o;o>>=1) s += __shfl_xor(s, o);
  if(t == 0) mask[i] = (s != 0.0f) ? 1.0f : 0.0f;
  __shared__ float xr[DIN];
  xr[t] = xv;
  __syncthreads();
  int dg = deg[i]; dg = dg > N-1 ? N-1 : dg;
  float a0 = nodeb[t]      + degemb[dg*D + t];
  float a1 = nodeb[t + 64] + degemb[dg*D + t + 64];
  #pragma unroll
  for(int u=0; u<DIN; ++u){
    float xu = xr[u];
    a0 = fmaf(xu, nodeW[u*D + t],      a0);
    a1 = fmaf(xu, nodeW[u*D + t + 64], a1);
  }
  h[i*D + t]      = a0;
  h[i*D + t + 64] = a1;
}

// ---------------------------------------------------------------- bias (masked, bf16)
__global__ void k_bias(const int* __restrict__ spl, const float* __restrict__ ef,
                       const float* __restrict__ spe, const float* __restrict__ eW,
                       const float* __restrict__ eb, const float* __restrict__ mask,
                       u16* __restrict__ biasm){
  int idx = blockIdx.x*blockDim.x + threadIdx.x;   // < N*N
  int i = idx / N, j = idx % N;
  float wm0 = (eW[0] + eW[1] + eW[2] + eW[3])  * 0.25f;
  float wm1 = (eW[4] + eW[5] + eW[6] + eW[7])  * 0.25f;
  float wm2 = (eW[8] + eW[9] + eW[10]+ eW[11]) * 0.25f;
  float wm3 = (eW[12]+ eW[13]+ eW[14]+ eW[15]) * 0.25f;
  float bm  = (eb[0] + eb[1] + eb[2] + eb[3])  * 0.25f;
  float4 e4 = reinterpret_cast<const float4*>(ef)[idx];
  float em = fmaf(e4.x, wm0, fmaf(e4.y, wm1, fmaf(e4.z, wm2, fmaf(e4.w, wm3, bm))));
  float b = spe[spl[idx]] + em;
  float mk = mask[i]*mask[j];
  biasm[idx] = f2bf((mk != 0.0f) ? b : NEGV);
}

// ---------------------------------------------------------------- layernorm
__global__ void k_ln(const float* __restrict__ in, const float* __restrict__ g,
                     const float* __restrict__ b, float* __restrict__ out){
  const int w = threadIdx.x >> 6, lane = threadIdx.x & 63;
  const int row = blockIdx.x*4 + w;
  const float* r = in + row*D;
  float v0 = r[lane], v1 = r[lane + 64];
  float s = v0 + v1, sq = v0*v0 + v1*v1;
  #pragma unroll
  for(int o=32;o;o>>=1){ s += __shfl_xor(s, o); sq += __shfl_xor(sq, o); }
  float mean = s*(1.0f/128.0f);
  float var  = sq*(1.0f/128.0f) - mean*mean;
  float inv  = rsqrtf(var + 1e-5f);
  out[row*D + lane]      = (v0 - mean)*inv*g[lane]      + b[lane];
  out[row*D + lane + 64] = (v1 - mean)*inv*g[lane + 64] + b[lane + 64];
}

// ---------------------------------------------------------------- weight prep: fp32 [K][128] -> bf16 Bt [128][K]
// 27 128x128 matrices: z<24 = qkv (z = l*12 + which*4 + head), z=24,25 ffW, z=26 outW
__global__ __launch_bounds__(256) void k_wt_all(const float* __restrict__ Wq, const float* __restrict__ Wk,
    const float* __restrict__ Wv, const float* __restrict__ ffW, const float* __restrict__ outW,
    u16* __restrict__ wt_qkv, u16* __restrict__ wt_ff, u16* __restrict__ wt_out){
  __shared__ float t[32][33];
  const int z = blockIdx.y;
  const float* src; u16* dst;
  if(z < 24){
    int l = z/12, r = z%12;
    const float* W = (r>>2)==0 ? Wq : (r>>2)==1 ? Wk : Wv;
    src = W + (size_t)(l*4 + (r&3))*16384;
    dst = wt_qkv + (size_t)z*16384;
  } else if(z < 26){
    src = ffW + (size_t)(z-24)*16384; dst = wt_ff + (size_t)(z-24)*16384;
  } else { src = outW; dst = wt_out; }
  const int ki = blockIdx.x & 3, ni = blockIdx.x >> 2;
  const int tid = threadIdx.x;
  #pragma unroll
  for(int i=0;i<4;i++){
    int idx = tid + i*256, r = idx>>5, c = idx&31;
    t[r][c] = src[(size_t)(ki*32+r)*128 + ni*32 + c];
  }
  __syncthreads();
  #pragma unroll
  for(int i=0;i<4;i++){
    int idx = tid + i*256, r = idx>>5, c = idx&31;
    dst[(size_t)(ni*32+r)*128 + ki*32 + c] = f2bf(t[c][r]);
  }
}

// Wo: fp32 [512][128] -> bf16 [128][512], per layer (blockIdx.y)
__global__ __launch_bounds__(256) void k_wt_wo(const float* __restrict__ Wo, u16* __restrict__ wt_wo){
  __shared__ float t[32][33];
  const int l = blockIdx.y;
  const float* src = Wo + (size_t)l*65536;
  u16* dst = wt_wo + (size_t)l*65536;
  const int ki = blockIdx.x & 15, ni = blockIdx.x >> 4;
  const int tid = threadIdx.x;
  #pragma unroll
  for(int i=0;i<4;i++){
    int idx = tid + i*256, r = idx>>5, c = idx&31;
    t[r][c] = src[(size_t)(ki*32+r)*128 + ni*32 + c];
  }
  __syncthreads();
  #pragma unroll
  for(int i=0;i<4;i++){
    int idx = tid + i*256, r = idx>>5, c = idx&31;
    dst[(size_t)(ni*32+r)*512 + ki*32 + c] = f2bf(t[c][r]);
  }
}

// ---------------------------------------------------------------- bf16 MFMA GEMM, C[M,128] = A[M,K]@Bt^T + bias (+res)
// Block 256 (4 waves), 64 rows x 128 cols. A fp32 converted to bf16 during LDS staging.
// LDS layout identical to k_attn's verified swizzle: [row][16 chunks of 16B], chunk ^= row&15.
// mfma(Afrag_row=l16, Btfrag_row=l16) -> C[m = w*16 + g4*4+rg][n = nt*16 + l16].
template<int K, bool RES, bool BF16OUT>
__device__ __forceinline__ void mgemm_body(const float* __restrict__ A, const u16* __restrict__ Bt,
                                           const float* __restrict__ bias, const float* __restrict__ res,
                                           void* __restrict__ Cv){
  __shared__ u16 As[64*128];
  __shared__ u16 Bs[128*128];
  const int tid = threadIdx.x, w = tid>>6, lane = tid&63;
  const int g4 = lane>>4, l16 = lane&15;
  const int m0 = blockIdx.x*64;
  const int srow = tid>>4, sch = tid&15;
  f32x4 acc[8];
  #pragma unroll
  for(int nt=0;nt<8;++nt) acc[nt] = (f32x4){0.f,0.f,0.f,0.f};
  for(int k0 = 0; k0 < K; k0 += 128){
    __syncthreads();
    #pragma unroll
    for(int it=0;it<4;++it){
      int row = it*16 + srow;
      const float4* ap = reinterpret_cast<const float4*>(A + (size_t)(m0+row)*K + k0 + sch*8);
      float4 x0 = ap[0], x1 = ap[1];
      u16x4 p0, p1;
      p0.x=f2bf(x0.x); p0.y=f2bf(x0.y); p0.z=f2bf(x0.z); p0.w=f2bf(x0.w);
      p1.x=f2bf(x1.x); p1.y=f2bf(x1.y); p1.z=f2bf(x1.z); p1.w=f2bf(x1.w);
      u16* dst = &As[row*128 + ((sch ^ (row&15))*8)];
      *reinterpret_cast<u16x4*>(dst)     = p0;
      *reinterpret_cast<u16x4*>(dst + 4) = p1;
    }
    #pragma unroll
    for(int it=0;it<8;++it){
      int row = it*16 + srow;
      short8 b = *reinterpret_cast<const short8*>(Bt + (size_t)row*K + k0 + sch*8);
      *reinterpret_cast<short8*>(&Bs[row*128 + ((sch ^ (row&15))*8)]) = b;
    }
    __syncthreads();
    __builtin_amdgcn_s_setprio(1);
    #pragma unroll
    for(int c=0;c<4;++c){
      short8 af = *reinterpret_cast<const short8*>(&As[(w*16+l16)*128 + (((c*4+g4) ^ l16)*8)]);
      #pragma unroll
      for(int nt=0;nt<8;++nt){
        short8 bf = *reinterpret_cast<const short8*>(&Bs[(nt*16+l16)*128 + (((c*4+g4) ^ l16)*8)]);
        acc[nt] = __builtin_amdgcn_mfma_f32_16x16x32_bf16(af, bf, acc[nt], 0, 0, 0);
      }
    }
    __builtin_amdgcn_s_setprio(0);
  }
  const int mrow = m0 + w*16 + g4*4;
  #pragma unroll
  for(int nt=0;nt<8;++nt){
    const int col = nt*16 + l16;
    float bi = bias[col];
    #pragma unroll
    for(int rg=0;rg<4;++rg){
      float v = acc[nt][rg] + bi;
      if(RES) v += res[(size_t)(mrow+rg)*128 + col];
      if(BF16OUT) ((u16*)Cv)[(size_t)(mrow+rg)*128 + col] = f2bf(v);
      else        ((float*)Cv)[(size_t)(mrow+rg)*128 + col] = v;
    }
  }
}

// grid (N/64, 12): z = which*4 + head
__global__ __launch_bounds__(256) void k_mqkv(const float* __restrict__ xln, const u16* __restrict__ wt_qkv,
    const float* __restrict__ bq, const float* __restrict__ bk, const float* __restrict__ bv,
    u16* __restrict__ q, u16* __restrict__ k, u16* __restrict__ v, int l){
  const int z = blockIdx.y, which = z>>2, head = z&3;
  const u16* Bt = wt_qkv + (size_t)(l*12 + z)*16384;
  const float* bb = (which==0 ? bq : which==1 ? bk : bv) + (l*H + head)*D;
  u16* out = (which==0 ? q : which==1 ? k : v) + (size_t)head*N*D;
  mgemm_body<128,false,true>(xln, Bt, bb, nullptr, out);
}

__global__ __launch_bounds__(256) void k_mwo(const float* __restrict__ ocat, const u16* __restrict__ wt_wo,
    const float* __restrict__ bo, const float* __restrict__ hres, float* __restrict__ xout, int l){
  mgemm_body<512,true,false>(ocat, wt_wo + (size_t)l*65536, bo + l*D, hres, xout);
}

__global__ __launch_bounds__(256) void k_mff(const float* __restrict__ xln, const u16* __restrict__ wt_ff,
    const float* __restrict__ ffb, const float* __restrict__ xout, float* __restrict__ h, int l){
  mgemm_body<128,true,false>(xln, wt_ff + (size_t)l*16384, ffb + l*D, xout, h);
}

__global__ __launch_bounds__(256) void k_mout(const float* __restrict__ h, const u16* __restrict__ wt_out,
    const float* __restrict__ outb, float* __restrict__ out){
  mgemm_body<128,false,false>(h, wt_out, outb, nullptr, out);
}

// ---------------------------------------------------------------- V transpose: [h][n][d] -> [h][d][n]
__global__ __launch_bounds__(256) void k_vt(const u16* __restrict__ vb, u16* __restrict__ vT){
  __shared__ u16 t[32][33];
  const int n0 = blockIdx.x*32, d0 = blockIdx.y*32, head = blockIdx.z;
  const int tid = threadIdx.x;
  #pragma unroll
  for(int i=0;i<4;i++){
    int idx = tid + i*256, r = idx >> 5, c = idx & 31;
    t[r][c] = vb[((size_t)head*N + n0 + r)*D + d0 + c];
  }
  __syncthreads();
  #pragma unroll
  for(int i=0;i<4;i++){
    int idx = tid + i*256, r = idx >> 5, c = idx & 31;
    vT[((size_t)head*D + d0 + r)*N + n0 + c] = t[c][r];
  }
}

// ---------------------------------------------------------------- MFMA flash attention, LDS-staged K/V
// Block = 256 thr (4 waves), 64 q-rows (16/wave); grid (N/64, H, SPLIT).
__global__ __launch_bounds__(256) void k_attn(const u16* __restrict__ q, const u16* __restrict__ k,
                     const u16* __restrict__ vT, const u16* __restrict__ biasm,
                     float* __restrict__ opart, float* __restrict__ mpart, float* __restrict__ lpart,
                     int kvlen){
  const int tid  = threadIdx.x;
  const int w    = tid >> 6;
  const int lane = tid & 63;
  const int g4 = lane >> 4, l16 = lane & 15;
  const int head = blockIdx.y, sp = blockIdx.z;
  const int r0 = blockIdx.x*64 + w*16;
  __shared__ u16 Ks[64*128];          // [key][128 dims], swizzled
  __shared__ u16 Vs[64*128];          // [d&63][seg=d>>6 | 64 keys], swizzled
  __shared__ u16 P[4][16][40];        // per-wave P, padded stride

  const u16* qbase = q + ((size_t)head*N + r0)*D;
  short8 qf[4];
  #pragma unroll
  for(int c=0;c<4;c++)
    qf[c] = *reinterpret_cast<const short8*>(qbase + l16*D + c*32 + g4*8);

  f32x4 o[8];
  #pragma unroll
  for(int dt=0;dt<8;dt++) o[dt] = (f32x4){0.f,0.f,0.f,0.f};
  float m = -INFINITY, lsum = 0.0f;

  const u16* kh   = k  + (size_t)head*N*D;
  const u16* vTh  = vT + (size_t)head*D*N;
  const u16* brow = biasm + (size_t)(r0 + l16)*N;
  const int kv0 = sp*kvlen;

  const int krow = tid >> 4, kch = tid & 15;
  const int vrow = tid >> 3, vch = tid & 7;

  for(int j0 = kv0; j0 < kv0 + kvlen; j0 += 64){
    short8 kreg[4], vreg[4];
    #pragma unroll
    for(int it=0; it<4; ++it)
      kreg[it] = *reinterpret_cast<const short8*>(kh + (size_t)(j0 + it*16 + krow)*D + kch*8);
    #pragma unroll
    for(int it=0; it<4; ++it)
      vreg[it] = *reinterpret_cast<const short8*>(vTh + (size_t)(it*32 + vrow)*N + j0 + vch*8);
    u16x4 bb[4];
    #pragma unroll
    for(int z=0; z<4; ++z)
      bb[z] = *reinterpret_cast<const u16x4*>(brow + j0 + z*16 + g4*4);

    __syncthreads();
    #pragma unroll
    for(int it=0; it<4; ++it){
      int row = it*16 + krow;
      *reinterpret_cast<short8*>(&Ks[row*128 + ((kch ^ (row&15))*8)]) = kreg[it];
    }
    #pragma unroll
    for(int it=0; it<4; ++it){
      int d = it*32 + vrow;
      int row = d & 63, ch = ((d>>6)<<3) | vch;
      *reinterpret_cast<short8*>(&Vs[row*128 + ((ch ^ (row&15))*8)]) = vreg[it];
    }
    __syncthreads();

    #pragma unroll
    for(int ks=0; ks<2; ++ks){
      short8 kf[8];
      const int rowA = ks*32 + l16, rowB = rowA + 16;
      #pragma unroll
      for(int c=0;c<4;c++){
        kf[c]   = *reinterpret_cast<const short8*>(&Ks[rowA*128 + (((c*4+g4) ^ l16)*8)]);
        kf[4+c] = *reinterpret_cast<const short8*>(&Ks[rowB*128 + (((c*4+g4) ^ l16)*8)]);
      }
      f32x4 sA = (f32x4){0.f,0.f,0.f,0.f}, sB = sA;
      __builtin_amdgcn_s_setprio(1);
      #pragma unroll
      for(int c=0;c<4;c++){
        sA = __builtin_amdgcn_mfma_f32_16x16x32_bf16(kf[c],   qf[c], sA, 0, 0, 0);
        sB = __builtin_amdgcn_mfma_f32_16x16x32_bf16(kf[4+c], qf[c], sB, 0, 0, 0);
      }
      __builtin_amdgcn_s_setprio(0);
      u16x4 bA = bb[2*ks], bB = bb[2*ks+1];
      sA[0] = fmaf(sA[0], SCALE, bf2f(bA.x)); sA[1] = fmaf(sA[1], SCALE, bf2f(bA.y));
      sA[2] = fmaf(sA[2], SCALE, bf2f(bA.z)); sA[3] = fmaf(sA[3], SCALE, bf2f(bA.w));
      sB[0] = fmaf(sB[0], SCALE, bf2f(bB.x)); sB[1] = fmaf(sB[1], SCALE, bf2f(bB.y));
      sB[2] = fmaf(sB[2], SCALE, bf2f(bB.z)); sB[3] = fmaf(sB[3], SCALE, bf2f(bB.w));
      float pmax = fmaxf(fmaxf(fmaxf(sA[0],sA[1]), fmaxf(sA[2],sA[3])),
                         fmaxf(fmaxf(sB[0],sB[1]), fmaxf(sB[2],sB[3])));
      pmax = fmaxf(pmax, __shfl_xor(pmax, 16));
      pmax = fmaxf(pmax, __shfl_xor(pmax, 32));
      if(!__all(pmax - m <= 8.0f)){
        float mnew = fmaxf(m, pmax);
        float corr = __expf(m - mnew);
        lsum *= corr;
        float c0 = __shfl(corr, (lane & 48) | (g4*4 + 0));
        float c1 = __shfl(corr, (lane & 48) | (g4*4 + 1));
        float c2 = __shfl(corr, (lane & 48) | (g4*4 + 2));
        float c3 = __shfl(corr, (lane & 48) | (g4*4 + 3));
        #pragma unroll
        for(int dt=0;dt<8;dt++){
          o[dt][0] *= c0; o[dt][1] *= c1; o[dt][2] *= c2; o[dt][3] *= c3;
        }
        m = mnew;
      }
      f32x4 pA, pB;
      #pragma unroll
      for(int rg=0;rg<4;rg++){ pA[rg] = __expf(sA[rg] - m); pB[rg] = __expf(sB[rg] - m); }
      float ps = (pA[0]+pA[1]) + (pA[2]+pA[3]) + ((pB[0]+pB[1]) + (pB[2]+pB[3]));
      ps += __shfl_xor(ps, 16);
      ps += __shfl_xor(ps, 32);
      lsum += ps;
      u16x4 wa, wb;
      wa.x = f2bf(pA[0]); wa.y = f2bf(pA[1]); wa.z = f2bf(pA[2]); wa.w = f2bf(pA[3]);
      wb.x = f2bf(pB[0]); wb.y = f2bf(pB[1]); wb.z = f2bf(pB[2]); wb.w = f2bf(pB[3]);
      *reinterpret_cast<u16x4*>(&P[w][l16][g4*4])      = wa;
      *reinterpret_cast<u16x4*>(&P[w][l16][16 + g4*4]) = wb;
      short8 pf = *reinterpret_cast<const short8*>(&P[w][l16][g4*8]);
      __builtin_amdgcn_s_setprio(1);
      #pragma unroll
      for(int dt=0;dt<8;dt++){
        int d = dt*16 + l16;
        int row = d & 63;
        int ch  = ((dt>>2)<<3) | (ks<<2) | g4;
        short8 vf = *reinterpret_cast<const short8*>(&Vs[row*128 + ((ch ^ l16)*8)]);
        o[dt] = __builtin_amdgcn_mfma_f32_16x16x32_bf16(pf, vf, o[dt], 0, 0, 0);
      }
      __builtin_amdgcn_s_setprio(0);
    }
  }

  float* ob = opart + ((size_t)((sp*H + head)*N) + r0)*D;
  #pragma unroll
  for(int dt=0;dt<8;dt++){
    #pragma unroll
    for(int rg=0;rg<4;rg++)
      ob[(size_t)(g4*4+rg)*D + dt*16 + l16] = o[dt][rg];
  }
  if(g4 == 0){
    mpart[(size_t)(sp*H + head)*N + r0 + l16] = m;
    lpart[(size_t)(sp*H + head)*N + r0 + l16] = lsum;
  }
}

// ---------------------------------------------------------------- split-K combine
template<int S>
__global__ __launch_bounds__(256) void k_comb(const float* __restrict__ opart,
                      const float* __restrict__ mpart, const float* __restrict__ lpart,
                      const float* __restrict__ mask, float* __restrict__ ocat){
  int idx = blockIdx.x*256 + threadIdx.x;          // < H*N*D
  int d = idx & (D-1);
  int r = (idx >> 7) % N;
  int h = idx / (N*D);
  float mv[S], lv[S];
  float M = -INFINITY;
  #pragma unroll
  for(int s=0;s<S;s++){
    size_t p = (size_t)(s*H + h)*N + r;
    mv[s] = mpart[p]; lv[s] = lpart[p];
    M = fmaxf(M, mv[s]);
  }
  float denom = 0.f, val = 0.f;
  #pragma unroll
  for(int s=0;s<S;s++){
    size_t p = (size_t)(s*H + h)*N + r;
    float wgt = __expf(mv[s] - M);
    denom = fmaf(lv[s], wgt, denom);
    val   = fmaf(opart[p*D + d], wgt, val);
  }
  ocat[(size_t)r*(H*D) + h*D + d] = val * (mask[r] / denom);
}

// ---------------------------------------------------------------- launch
extern "C" void kernel_launch(void* const* d_in, const int* in_sizes, int n_in,
                              void* d_out, int out_size, void* d_ws, size_t ws_size,
                              hipStream_t stream){
  const float* x      = (const float*)d_in[0];
  const int*   ei     = (const int*)  d_in[1];
  const int*   spl    = (const int*)  d_in[2];
  const float* ef     = (const float*)d_in[3];
  const float* nodeW  = (const float*)d_in[4];
  const float* nodeb  = (const float*)d_in[5];
  const float* degemb = (const float*)d_in[6];
  const float* spe    = (const float*)d_in[7];
  const float* eW     = (const float*)d_in[8];
  const float* eb     = (const float*)d_in[9];
  const float* ln1g   = (const float*)d_in[10];
  const float* ln1b   = (const float*)d_in[11];
  const float* Wq     = (const float*)d_in[12];
  const float* bq     = (const float*)d_in[13];
  const float* Wk     = (const float*)d_in[14];
  const float* bk     = (const float*)d_in[15];
  const float* Wv     = (const float*)d_in[16];
  const float* bv     = (const float*)d_in[17];
  const float* Wo     = (const float*)d_in[18];
  const float* bo     = (const float*)d_in[19];
  const float* ln2g   = (const float*)d_in[20];
  const float* ln2b   = (const float*)d_in[21];
  const float* ffW    = (const float*)d_in[22];
  const float* ffb    = (const float*)d_in[23];
  const float* outW   = (const float*)d_in[24];
  const float* outb   = (const float*)d_in[25];

  constexpr size_t WT_ELEMS = 24*16384 + 2*16384 + 16384 + 2*65536;  // 573440 bf16
  auto needed = [](int s)->size_t{
    size_t fl = 8192 + 3*(size_t)N*D + (size_t)N*H*D;          // fp32 elems
    size_t bf = 4*(size_t)H*N*D + (size_t)N*N;                 // bf16 elems
    size_t pf = (size_t)s*H*N*D + 2*(size_t)s*H*N;             // fp32 partials
    return fl*4 + bf*2 + pf*4 + WT_ELEMS*2;
  };
  int S = 2;
  if(needed(4) <= ws_size) S = 4;

  float* ws   = (float*)d_ws;
  int*   deg  = (int*)ws;                       // N ints (4096-float slot)
  float* mask = ws + 4096;                      // N (4096-float slot)
  float* h    = ws + 8192;                      // N*D
  float* xln  = h    + N*D;
  float* xout = xln  + N*D;
  float* ocat = xout + N*D;                     // N*H*D fp32
  u16*   qb   = (u16*)(ocat + N*H*D);           // H*N*D bf16 each
  u16*   kb   = qb + (size_t)H*N*D;
  u16*   vb   = kb + (size_t)H*N*D;
  u16*   vT   = vb + (size_t)H*N*D;
  u16*   biasm= vT + (size_t)H*N*D;             // N*N bf16
  float* opart= (float*)(biasm + (size_t)N*N);  // S*H*N*D
  float* mpart= opart + (size_t)S*H*N*D;        // S*H*N
  float* lpart= mpart + (size_t)S*H*N;          // S*H*N
  u16*   wt_qkv = (u16*)(lpart + (size_t)S*H*N);// 24*16384
  u16*   wt_ff  = wt_qkv + 24*16384;            // 2*16384
  u16*   wt_out = wt_ff  + 2*16384;             // 16384
  u16*   wt_wo  = wt_out + 16384;               // 2*65536

  k_wt_all<<<dim3(16, 27), 256, 0, stream>>>(Wq, Wk, Wv, ffW, outW, wt_qkv, wt_ff, wt_out);
  k_wt_wo<<<dim3(64, 2), 256, 0, stream>>>(Wo, wt_wo);
  k_zero_deg<<<(N+255)/256, 256, 0, stream>>>(deg);
  k_deg<<<(E+255)/256, 256, 0, stream>>>(ei, deg);
  k_h0<<<N, 64, 0, stream>>>(x, nodeW, nodeb, degemb, deg, mask, h);
  k_bias<<<(N*N)/256, 256, 0, stream>>>(spl, ef, spe, eW, eb, mask, biasm);

  for(int l = 0; l < 2; ++l){
    k_ln<<<N/4, 256, 0, stream>>>(h, ln1g + l*D, ln1b + l*D, xln);
    k_mqkv<<<dim3(N/64, 12), 256, 0, stream>>>(xln, wt_qkv, bq, bk, bv, qb, kb, vb, l);
    k_vt<<<dim3(N/32, D/32, H), 256, 0, stream>>>(vb, vT);
    k_attn<<<dim3(N/64, H, S), 256, 0, stream>>>(qb, kb, vT, biasm, opart, mpart, lpart, N/S);
    if(S == 4) k_comb<4><<<(H*N*D)/256, 256, 0, stream>>>(opart, mpart, lpart, mask, ocat);
    else       k_comb<2><<<(H*N*D)/256, 256, 0, stream>>>(opart, mpart, lpart, mask, ocat);
    k_mwo<<<N/64, 256, 0, stream>>>(ocat, wt_wo, bo, h, xout, l);
    k_ln<<<N/4, 256, 0, stream>>>(xout, ln2g + l*D, ln2b + l*D, xln);
    k_mff<<<N/64, 256, 0, stream>>>(xln, wt_ff, ffb, xout, h, l);
  }
  k_mout<<<N/64, 256, 0, stream>>>(h, wt_out, outb, (float*)d_out);
}